// Round 3
// baseline (264.759 us; speedup 1.0000x reference)
//
#include <hip/hip_runtime.h>
#include <math.h>
#include <stdint.h>

#define B_    8
#define N_    3136
#define DIM_  147
#define KP_   160
#define TOK_  (B_*N_)      // 25088
#define QKV3_ 192
#define NSPLIT 4

typedef __attribute__((ext_vector_type(4)))  float f32x4;
typedef __attribute__((ext_vector_type(16))) float f32x16;
typedef __attribute__((ext_vector_type(4)))  unsigned int u32x4;
typedef __attribute__((ext_vector_type(2)))  unsigned int u32x2;
typedef __attribute__((ext_vector_type(8)))  short short8;
typedef float f32x4u __attribute__((ext_vector_type(4), aligned(4)));  // 4B-aligned vector load
typedef union { short8 s; u32x4 u; } pk8;

static __device__ __forceinline__ unsigned short f2b(float f){
  unsigned int u = __float_as_uint(f);
  u += 0x7fffu + ((u>>16)&1u);          // RNE
  return (unsigned short)(u>>16);
}
static __device__ __forceinline__ unsigned int pk2(float a, float b){   // RNE pack
  return ((unsigned int)f2b(b)<<16) | (unsigned int)f2b(a);
}
static __device__ __forceinline__ unsigned int pk2t(float a, float b){  // trunc pack (P only)
  return (__float_as_uint(b) & 0xffff0000u) | (__float_as_uint(a)>>16);
}
static __device__ __forceinline__ float b2f(unsigned short s){
  return __uint_as_float(((unsigned int)s)<<16);
}

// async global->LDS, 16 B per lane; LDS dest = uniform base + lane*16
#define GLD16(gp, lp) __builtin_amdgcn_global_load_lds( \
    reinterpret_cast<const uint32_t __attribute__((address_space(1)))*>(reinterpret_cast<uintptr_t>(gp)), \
    reinterpret_cast<uint32_t __attribute__((address_space(3)))*>(reinterpret_cast<uintptr_t>(lp)), \
    16, 0, 0)

// ---------------------------------------------------------------- K1: fused LN1 + QKV GEMM
__global__ __launch_bounds__(256) void k_qkv(const float* __restrict__ x,
                                             const float* __restrict__ w1,
                                             const float* __restrict__ b1,
                                             const float* __restrict__ qkvw,
                                             const float* __restrict__ scale,
                                             unsigned short* __restrict__ qb,
                                             unsigned short* __restrict__ kb,
                                             unsigned short* __restrict__ vtb,
                                             unsigned short* __restrict__ vfb){
  __shared__ alignas(16) unsigned short Wb[192*168];  // 64512 B; aliased by A_ and VT
  unsigned short* A_ = Wb;
  unsigned short* VT = Wb;
  int tid = threadIdx.x;
  int w = tid>>6, lane = tid&63, quad = lane>>4, l16 = lane&15;
  int t0 = blockIdx.x*64;
  float sc2 = scale[0] * 1.44269504089f;

  #pragma unroll
  for(int half=0; half<2; half++){
    int g = half*32 + (tid>>3), e = tid&7;
    const float* xr = x + (size_t)(t0+g)*147;
    f32x4u xv[5];
    float s = 0.f, sq = 0.f;
    #pragma unroll
    for(int j=0;j<5;j++){
      int k = e + 8*j;                      // chunk index, cols 4k..4k+3
      int keff = (k > 36) ? 36 : k;         // clamp addr (masked lanes reuse chunk 36)
      f32x4u v = *(const f32x4u*)(xr + 4*keff);
      if(j == 4){                           // k in [32,39]: mask tail
        v[0] = (k<=36) ? v[0] : 0.f;
        v[1] = (k<=36) ? v[1] : 0.f;
        v[2] = (k<=36) ? v[2] : 0.f;
        v[3] = (k< 36) ? v[3] : 0.f;        // col 147 invalid at k==36
      }
      xv[j] = v;
      s  += (v[0]+v[1]) + (v[2]+v[3]);
      sq += (v[0]*v[0]+v[1]*v[1]) + (v[2]*v[2]+v[3]*v[3]);
    }
    s  += __shfl_xor(s,1,64);  s  += __shfl_xor(s,2,64);  s  += __shfl_xor(s,4,64);
    sq += __shfl_xor(sq,1,64); sq += __shfl_xor(sq,2,64); sq += __shfl_xor(sq,4,64);
    float mean = s*(1.f/147.f);
    float var  = sq*(1.f/147.f) - mean*mean;
    float rstd = rsqrtf(var + 1e-5f);
    #pragma unroll
    for(int j=0;j<5;j++){
      int k = e + 8*j;
      unsigned int lo = 0u, hi = 0u;
      if(k <= 36){
        int c0 = 4*k;
        int c3 = (k==36) ? 146 : c0+3;      // don't read w1/b1 past 146
        float y0 = (xv[j][0]-mean)*rstd*w1[c0]   + b1[c0];
        float y1 = (xv[j][1]-mean)*rstd*w1[c0+1] + b1[c0+1];
        float y2 = (xv[j][2]-mean)*rstd*w1[c0+2] + b1[c0+2];
        float y3 = (xv[j][3]-mean)*rstd*w1[c3]   + b1[c3];
        if(k == 36) y3 = 0.f;               // col 147 -> 0 (K padding)
        lo = pk2(y0,y1); hi = pk2(y2,y3);
      }
      *(u32x2*)(A_ + g*168 + 4*k) = (u32x2){lo,hi};   // k>36 lanes zero cols 148..159
    }
  }
  __syncthreads();
  short8 Af[5];
  #pragma unroll
  for(int kk=0;kk<5;kk++)
    Af[kk] = *(const short8*)(A_ + (w*16+l16)*168 + kk*32 + quad*8);
  __syncthreads();
  {
    // stage qkv weights: convert f32 -> bf16 inline
    unsigned int* dst = (unsigned int*)Wb;
    #pragma unroll
    for(int rep=0; rep<15; rep++){
      int idx = rep*256 + tid;
      int row = idx/20, c = idx - row*20;
      u32x4 o = (u32x4){0u,0u,0u,0u};
      if(c < 19){
        const float* sp = qkvw + row*147 + c*8;
        f32x4u a = *(const f32x4u*)sp;
        o[0] = pk2(a[0],a[1]);
        if(c < 18){
          f32x4u bv = *(const f32x4u*)(sp+4);
          o[1] = pk2(a[2],a[3]);
          o[2] = pk2(bv[0],bv[1]);
          o[3] = pk2(bv[2],bv[3]);
        } else {
          o[1] = pk2(a[2],0.f);             // col 147 of row = next row's elem -> masked
        }
      }
      *(u32x4*)(dst + row*84 + c*4) = o;
    }
  }
  __syncthreads();
  f32x4 acc[12];
  #pragma unroll
  for(int i=0;i<12;i++) acc[i] = (f32x4){0.f,0.f,0.f,0.f};
  #pragma unroll
  for(int nt=0;nt<12;nt++){
    #pragma unroll
    for(int kk=0;kk<5;kk++){
      short8 Bf = *(const short8*)(Wb + (nt*16+l16)*168 + kk*32 + quad*8);
      acc[nt] = __builtin_amdgcn_mfma_f32_16x16x32_bf16(Af[kk], Bf, acc[nt], 0,0,0);
    }
  }
  #pragma unroll
  for(int nt=0;nt<12;nt++){
    int o = nt*16 + l16;
    #pragma unroll
    for(int r=0;r<4;r++){
      int tl = w*16 + quad*4 + r;
      int mg = t0 + tl;
      float val = acc[nt][r];
      if(o < 64)        qb[(size_t)mg*64 + o]        = f2b(val*sc2);
      else if(o < 128)  kb[(size_t)mg*64 + (o-64)]   = f2b(val);
      else              vfb[(size_t)mg*64 + (o-128)] = f2b(val);
    }
  }
  __syncthreads();
  #pragma unroll
  for(int nt=8;nt<12;nt++){
    int hd = (nt-8)*16 + l16;
    #pragma unroll
    for(int r=0;r<4;r++)
      VT[hd*72 + (w*16 + quad*4 + r)] = f2b(acc[nt][r]);
  }
  __syncthreads();
  {
    int b = t0 / N_, n0 = t0 - b*N_;
    const unsigned int* VT32 = (const unsigned int*)VT;
    unsigned int* vg = (unsigned int*)vtb + ((size_t)b*64)*(N_/2) + (n0>>1);
    #pragma unroll
    for(int rep=0;rep<8;rep++){
      int f = rep*256 + tid;
      int row = f>>5, c = f&31;
      vg[(size_t)row*(N_/2) + c] = VT32[row*36 + c];
    }
  }
}

// ---------------------------------------------------------------- K2: attention — R12: 4 waves / 128 q-rows per block
// Evidence (R2 rocprof): Occupancy 12% (~1 wave/SIMD), MfmaUtil 17%, VALU 28%, HBM 13% -> latency-bound.
// Fix: 256-thread blocks = 2 wave-pairs sharing one staged KV tile; pair w2 handles q-tile 2*qt+w2.
// Staging split 4 ways (waves 0,1 = K halves; waves 2,3 = V halves; 4 GLD16/wave/tile, vmcnt(4)).
// LDS unchanged (32KB dbuf + merge reuse) -> 4 blocks/CU x 4 waves = 4 waves/SIMD capacity.
// KV staged bytes halve (one tile serves 128 q-rows). Odd tile count: dead pair in 1/25 blocks, writes masked.
__global__ __launch_bounds__(256,4) void k_attn(const unsigned short* __restrict__ qb,
                                                const unsigned short* __restrict__ kb,
                                                const unsigned short* __restrict__ vtb,
                                                unsigned short* __restrict__ Opart,
                                                float* __restrict__ lpart){
  __shared__ alignas(16) unsigned int L[8192];   // 2 x (K 8KB | V 8KB) dbuf; reused for merge (16KB/pair)
  __shared__ float Lr[256];
  int tid = threadIdx.x;
  int s = tid>>6;                // wave id 0..3
  int w2 = s>>1;                 // q-pair index
  int w  = s&1;                  // kv-half for compute
  int lane = tid&63;
  int h = lane>>5, l32 = lane&31, l7 = l32&7;
  int qt = blockIdx.x, sp = blockIdx.y, b = blockIdx.z;
  int qtile = 2*qt + w2;         // 64-row q tile, 0..48 valid
  int live = (qtile < 49);
  int q0 = live ? qtile*64 : 0;  // clamp dead pair's reads to a valid tile
  int kv0 = (sp*49)>>2, kv1 = ((sp+1)*49)>>2;
  int nt = kv1 - kv0;

  // Q B-frags (32x32x16): n=l32 -> q=q0+32qh+l32; k=8h+i -> hd=16kc+8h+i
  short8 Qf[2][4];
  {
    const unsigned short* qg = qb + ((size_t)b*N_ + q0)*64;
    #pragma unroll
    for(int qh=0;qh<2;qh++)
      #pragma unroll
      for(int kc=0;kc<4;kc++)
        Qf[qh][kc] = *(const short8*)(qg + (32*qh + l32)*64 + 16*kc + 8*h);
  }
  // staging role: waves 0,1 stage K halves; waves 2,3 stage V halves (wh = half index)
  int isK = (s < 2);
  int wh  = s & 1;
  int offG[4];
  {
    int pl = lane>>3, cl = lane&7;
    #pragma unroll
    for(int rr=0;rr<4;rr++){
      int p = rr*8 + pl;
      int cx = cl ^ (p&7);                               // XOR col swizzle
      if(isK){
        int sig = (p & 0x13) | ((p&4)<<1) | ((p&8)>>1);  // swap bits 2<->3
        offG[rr] = (32*wh + sig)*128 + cx*16;            // K: sigma'd row, byte col
      } else {
        offG[rr] = (32*wh + p)*(N_*2) + cx*16;           // V^T: plain hd row
      }
    }
  }
  const char* sBase = isK ? ((const char*)kb  + (size_t)b*N_*128)
                          : ((const char*)vtb + (size_t)b*64*(size_t)(N_*2));
  int tileStride = isK ? 8192 : 128;
  int ldsOff = (isK ? 0 : 8192) + wh*4096;               // within 16KB tile buffer

  f32x16 O[2][2];
  #pragma unroll
  for(int qh=0;qh<2;qh++) for(int hdq=0;hdq<2;hdq++)
    #pragma unroll
    for(int r=0;r<16;r++) O[qh][hdq][r] = 0.f;
  float lracc[2][4];
  #pragma unroll
  for(int qh=0;qh<2;qh++)
    #pragma unroll
    for(int j=0;j<4;j++) lracc[qh][j] = 0.f;

  // prologue: stage tile kv0 into buffer 0 (each wave: its 4KB quarter)
  {
    const char* tp = sBase + (size_t)kv0*tileStride;
    #pragma unroll
    for(int rr=0;rr<4;rr++) GLD16(tp + offG[rr], (char*)L + ldsOff + rr*1024);
  }

  int cur = 0;
  for(int i=0;i<nt;i++){
    int kvt = kv0 + i;
    if(i+1 < nt){
      const char* tp = sBase + (size_t)(kvt+1)*tileStride;
      char* dst = (char*)L + (cur^1)*16384 + ldsOff;
      #pragma unroll
      for(int rr=0;rr<4;rr++) GLD16(tp + offG[rr], dst + rr*1024);
      asm volatile("s_waitcnt vmcnt(4)" ::: "memory");   // current tile's 4 done, next 4 in flight
    } else {
      asm volatile("s_waitcnt vmcnt(0)" ::: "memory");
    }
    __builtin_amdgcn_s_barrier();            // all waves' tile-i LDS quarters visible
    __builtin_amdgcn_sched_barrier(0);       // pin: no ds_read hoisted above barrier

    if(live){
      const unsigned short* Kh = (const unsigned short*)L + cur*8192 + w*2048;
      const unsigned short* Vh = (const unsigned short*)L + cur*8192 + 4096;

      short8 Kf[4];
      #pragma unroll
      for(int kc=0;kc<4;kc++)
        Kf[kc] = *(const short8*)(Kh + l32*64 + (((2*kc+h) ^ l7)&7)*8);
      #pragma unroll
      for(int qh=0;qh<2;qh++){
        f32x16 S;
        #pragma unroll
        for(int r=0;r<16;r++) S[r] = 0.f;
        #pragma unroll
        for(int kc=0;kc<4;kc++)
          S = __builtin_amdgcn_mfma_f32_32x32x16_bf16(Kf[kc], Qf[qh][kc], S, 0,0,0);
        f32x16 E;
        if(kvt == qtile){                // diagonal tile (wave-uniform branch)
          int dref = 32*qh + l32 - 32*w - 8*h;
          #pragma unroll
          for(int r=0;r<16;r++){
            int kvl = 16*((r>>3)&1) + 4*((r>>2)&1) + (r&3);
            float pv = (kvl == dref) ? 0.f : __builtin_amdgcn_exp2f(S[r]);
            E[r] = pv; lracc[qh][r&3] += pv;
          }
        } else {
          #pragma unroll
          for(int r=0;r<16;r++){
            float pv = __builtin_amdgcn_exp2f(S[r]);
            E[r] = pv; lracc[qh][r&3] += pv;
          }
        }
        pk8 Pb0, Pb1;
        Pb0.u = (u32x4){ pk2t(E[0],E[1]),   pk2t(E[2],E[3]),
                         pk2t(E[4],E[5]),   pk2t(E[6],E[7]) };
        Pb1.u = (u32x4){ pk2t(E[8],E[9]),   pk2t(E[10],E[11]),
                         pk2t(E[12],E[13]), pk2t(E[14],E[15]) };
        #pragma unroll
        for(int hdq=0;hdq<2;hdq++){
          short8 Vf0 = *(const short8*)(Vh + (32*hdq + l32)*64 + (((4*w + h) ^ l7)&7)*8);
          short8 Vf1 = *(const short8*)(Vh + (32*hdq + l32)*64 + (((4*w + 2 + h) ^ l7)&7)*8);
          O[qh][hdq] = __builtin_amdgcn_mfma_f32_32x32x16_bf16(Vf0, Pb0.s, O[qh][hdq], 0,0,0);
          O[qh][hdq] = __builtin_amdgcn_mfma_f32_32x32x16_bf16(Vf1, Pb1.s, O[qh][hdq], 0,0,0);
        }
      }
    }
    __builtin_amdgcn_sched_barrier(0);       // pin: no ds_read sunk below WAR barrier
    asm volatile("" ::: "memory");
    __builtin_amdgcn_s_barrier();            // WAR: buf cur free for overwrite at i+1
    cur ^= 1;
  }
  float lr[2];
  #pragma unroll
  for(int qh=0;qh<2;qh++)
    lr[qh] = (lracc[qh][0] + lracc[qh][1]) + (lracc[qh][2] + lracc[qh][3]);
  lr[0] += __shfl_xor(lr[0],32,64);
  lr[1] += __shfl_xor(lr[1],32,64);
  __syncthreads();                     // L free (all tile reads done)
  unsigned int* Lp = L + w2*4096;      // per-pair 16KB merge region
  float* Lrp = Lr + w2*128;
  if(w == 0){
    #pragma unroll
    for(int qh=0;qh<2;qh++)
      #pragma unroll
      for(int hdq=0;hdq<2;hdq++)
        #pragma unroll
        for(int r=0;r<16;r++)
          Lp[(qh*32 + hdq*16 + r)*64 + lane] = __float_as_uint(O[qh][hdq][r]);
    Lrp[lane]      = lr[0];
    Lrp[64 + lane] = lr[1];
  }
  __syncthreads();
  if(w == 1){
    #pragma unroll
    for(int qh=0;qh<2;qh++)
      #pragma unroll
      for(int hdq=0;hdq<2;hdq++)
        #pragma unroll
        for(int r=0;r<16;r++)
          O[qh][hdq][r] += __uint_as_float(Lp[(qh*32 + hdq*16 + r)*64 + lane]);
    float lt0 = lr[0] + Lrp[lane];
    float lt1 = lr[1] + Lrp[64 + lane];
    size_t lb = (size_t)sp*TOK_ + (size_t)b*N_ + q0;
    if(live && lane < 32){ lpart[lb + lane] = lt0; lpart[lb + 32 + lane] = lt1; }
    // transpose O^T -> [q][hd] bf16 in Lp (in-wave DS ordering: reads above precede writes)
    #pragma unroll
    for(int qh=0;qh<2;qh++){
      int q = 32*qh + l32;
      #pragma unroll
      for(int hdq=0;hdq<2;hdq++)
        #pragma unroll
        for(int k2=0;k2<8;k2++){
          int idx = 16*hdq + 4*(k2>>1) + 2*h + (k2&1);
          Lp[q*36 + idx] = pk2(O[qh][hdq][2*k2], O[qh][hdq][2*k2+1]);
        }
    }
    if(live){
      unsigned int* og = (unsigned int*)(Opart + ((size_t)sp*TOK_ + (size_t)b*N_ + q0)*64);
      #pragma unroll
      for(int rep=0;rep<8;rep++){
        int f = rep*64 + lane;
        int row = f>>3, c4 = f&7;
        *(u32x4*)(og + row*32 + c4*4) = *(const u32x4*)&Lp[row*36 + c4*4];
      }
    }
  }
}

// ---------------------------------------------------------------- K3: merge + proj + residual(v) + LN2 + MLP + residual
__global__ __launch_bounds__(256) void k_mlp(const unsigned short* __restrict__ Opart,
                                             const float* __restrict__ lpart,
                                             const unsigned short* __restrict__ vfb,
                                             const float* __restrict__ projw,
                                             const float* __restrict__ fc1w,
                                             const float* __restrict__ fc2w,
                                             const float* __restrict__ projb,
                                             const float* __restrict__ n2w,
                                             const float* __restrict__ n2b,
                                             const float* __restrict__ fc1b,
                                             const float* __restrict__ fc2b,
                                             float* __restrict__ out){
  __shared__ alignas(16) unsigned short Ws[3][64*72];
  __shared__ alignas(16) unsigned short Xs[64*72];
  unsigned int* Xs32 = (unsigned int*)Xs;
  int tid = threadIdx.x;
  int w = tid>>6, lane = tid&63, quad = lane>>4, l16 = lane&15;
  int t0 = blockIdx.x*64;

  {
    #pragma unroll
    for(int rep=0;rep<2;rep++){
      int f = rep*256 + tid;
      int row = f>>3, c = f&7;
      int so = (row<<6) + (c<<3);          // f32 src offset, 16B-aligned
      f32x4 a0 = *(const f32x4*)(projw + so), b0 = *(const f32x4*)(projw + so + 4);
      f32x4 a1 = *(const f32x4*)(fc1w  + so), b1v = *(const f32x4*)(fc1w  + so + 4);
      f32x4 a2 = *(const f32x4*)(fc2w  + so), b2 = *(const f32x4*)(fc2w  + so + 4);
      *(u32x4*)((unsigned int*)Ws[0] + row*36 + c*4) =
        (u32x4){pk2(a0[0],a0[1]),pk2(a0[2],a0[3]),pk2(b0[0],b0[1]),pk2(b0[2],b0[3])};
      *(u32x4*)((unsigned int*)Ws[1] + row*36 + c*4) =
        (u32x4){pk2(a1[0],a1[1]),pk2(a1[2],a1[3]),pk2(b1v[0],b1v[1]),pk2(b1v[2],b1v[3])};
      *(u32x4*)((unsigned int*)Ws[2] + row*36 + c*4) =
        (u32x4){pk2(a2[0],a2[1]),pk2(a2[2],a2[3]),pk2(b2[0],b2[1]),pk2(b2[2],b2[3])};
    }
  }
  #pragma unroll
  for(int i=0;i<2;i++){
    int f = i*256 + tid;
    int row = f>>3, c = f&7;
    float lo[4] = {0,0,0,0}, hi[4] = {0,0,0,0};
    float lsum = 0.f;
    #pragma unroll
    for(int s=0;s<NSPLIT;s++){
      u32x4 a = *((const u32x4*)(Opart + ((size_t)s*TOK_ + t0)*64) + row*8 + c);
      #pragma unroll
      for(int k=0;k<4;k++){
        lo[k] += __uint_as_float(a[k]<<16);
        hi[k] += __uint_as_float(a[k] & 0xffff0000u);
      }
      lsum += lpart[(size_t)s*TOK_ + t0 + row];
    }
    float linv = 1.f/lsum;
    u32x4 o;
    #pragma unroll
    for(int k=0;k<4;k++) o[k] = pk2(lo[k]*linv, hi[k]*linv);
    *(u32x4*)&Xs32[row*36 + c*4] = o;
  }
  __syncthreads();

  short8 Af[2];
  #pragma unroll
  for(int kk=0;kk<2;kk++)
    Af[kk] = *(const short8*)(Xs + (w*16+l16)*72 + kk*32 + quad*8);
  f32x4 acc[4];
  #pragma unroll
  for(int i=0;i<4;i++) acc[i] = (f32x4){0.f,0.f,0.f,0.f};
  #pragma unroll
  for(int jt=0;jt<4;jt++)
    #pragma unroll
    for(int kk=0;kk<2;kk++){
      short8 Bf = *(const short8*)(Ws[0] + (jt*16+l16)*72 + kk*32 + quad*8);
      acc[jt] = __builtin_amdgcn_mfma_f32_16x16x32_bf16(Af[kk], Bf, acc[jt], 0,0,0);
    }
  float xa[4][4];
  #pragma unroll
  for(int jt=0;jt<4;jt++){
    int col = jt*16 + l16;
    float pb = projb[col];
    #pragma unroll
    for(int r=0;r<4;r++){
      int tg = t0 + w*16 + quad*4 + r;
      xa[jt][r] = acc[jt][r] + pb + b2f(vfb[(size_t)tg*64 + col]);
    }
  }
  #pragma unroll
  for(int r=0;r<4;r++){
    float s = 0.f, sq = 0.f;
    #pragma unroll
    for(int jt=0;jt<4;jt++){ s += xa[jt][r]; sq += xa[jt][r]*xa[jt][r]; }
    s  += __shfl_xor(s,1,64);  s  += __shfl_xor(s,2,64);
    s  += __shfl_xor(s,4,64);  s  += __shfl_xor(s,8,64);
    sq += __shfl_xor(sq,1,64); sq += __shfl_xor(sq,2,64);
    sq += __shfl_xor(sq,4,64); sq += __shfl_xor(sq,8,64);
    float mu = s*(1.f/64.f);
    float var = sq*(1.f/64.f) - mu*mu;
    float rstd = rsqrtf(var + 1e-5f);
    #pragma unroll
    for(int jt=0;jt<4;jt++){
      int col = jt*16 + l16;
      Xs[(w*16+quad*4+r)*72 + col] = f2b((xa[jt][r]-mu)*rstd*n2w[col] + n2b[col]);
    }
  }
  #pragma unroll
  for(int kk=0;kk<2;kk++)
    Af[kk] = *(const short8*)(Xs + (w*16+l16)*72 + kk*32 + quad*8);
  f32x4 acc2[4];
  #pragma unroll
  for(int i=0;i<4;i++) acc2[i] = (f32x4){0.f,0.f,0.f,0.f};
  #pragma unroll
  for(int jt=0;jt<4;jt++)
    #pragma unroll
    for(int kk=0;kk<2;kk++){
      short8 Bf = *(const short8*)(Ws[1] + (jt*16+l16)*72 + kk*32 + quad*8);
      acc2[jt] = __builtin_amdgcn_mfma_f32_16x16x32_bf16(Af[kk], Bf, acc2[jt], 0,0,0);
    }
  #pragma unroll
  for(int jt=0;jt<4;jt++){
    int col = jt*16 + l16;
    float fb = fc1b[col];
    #pragma unroll
    for(int r=0;r<4;r++){
      float g = acc2[jt][r] + fb;
      float z = g*0.70710678118f;
      float az = fabsf(z);
      float t = 1.f/(1.f + 0.3275911f*az);
      float poly = ((((1.061405429f*t - 1.453152027f)*t + 1.421413741f)*t - 0.284496736f)*t + 0.254829592f)*t;
      float er = 1.f - poly*__builtin_amdgcn_exp2f(-az*az*1.44269504089f);
      er = (z < 0.f) ? -er : er;
      Xs[(w*16+quad*4+r)*72 + col] = f2b(0.5f*g*(1.f + er));
    }
  }
  #pragma unroll
  for(int kk=0;kk<2;kk++)
    Af[kk] = *(const short8*)(Xs + (w*16+l16)*72 + kk*32 + quad*8);
  f32x4 acc3[4];
  #pragma unroll
  for(int i=0;i<4;i++) acc3[i] = (f32x4){0.f,0.f,0.f,0.f};
  #pragma unroll
  for(int jt=0;jt<4;jt++)
    #pragma unroll
    for(int kk=0;kk<2;kk++){
      short8 Bf = *(const short8*)(Ws[2] + (jt*16+l16)*72 + kk*32 + quad*8);
      acc3[jt] = __builtin_amdgcn_mfma_f32_16x16x32_bf16(Af[kk], Bf, acc3[jt], 0,0,0);
    }
  #pragma unroll
  for(int jt=0;jt<4;jt++){
    int col = jt*16 + l16;
    float ob2 = fc2b[col];
    #pragma unroll
    for(int r=0;r<4;r++){
      int tg = t0 + w*16 + quad*4 + r;
      out[(size_t)tg*64 + col] = xa[jt][r] + acc3[jt][r] + ob2;
    }
  }
}

// ---------------------------------------------------------------- launch
extern "C" void kernel_launch(void* const* d_in, const int* in_sizes, int n_in,
                              void* d_out, int out_size, void* d_ws, size_t ws_size,
                              hipStream_t stream){
  const float* x     = (const float*)d_in[0];
  const float* n1w   = (const float*)d_in[1];
  const float* n1b   = (const float*)d_in[2];
  const float* qkvw  = (const float*)d_in[3];
  const float* scale = (const float*)d_in[4];
  const float* projw = (const float*)d_in[5];
  const float* projb = (const float*)d_in[6];
  const float* n2w   = (const float*)d_in[7];
  const float* n2b   = (const float*)d_in[8];
  const float* fc1w  = (const float*)d_in[9];
  const float* fc1b  = (const float*)d_in[10];
  const float* fc2w  = (const float*)d_in[11];
  const float* fc2b  = (const float*)d_in[12];

  char* base = (char*)d_ws;
  unsigned short* qb  = (unsigned short*)(base + 0);          //  3211264
  unsigned short* kb  = (unsigned short*)(base + 3211264);    //  3211264
  unsigned short* vtb = (unsigned short*)(base + 6422528);    //  3211264
  unsigned short* vfb = (unsigned short*)(base + 9633792);    //  3211264
  unsigned short* Op  = (unsigned short*)(base + 12845056);   // 12845056 (4 splits bf16)
  float*          lp  = (float*)(base + 25690112);            //   401408  -> total 26091520

  hipLaunchKernelGGL(k_qkv,  dim3(TOK_/64),    dim3(256), 0, stream,
                     x, n1w, n1b, qkvw, scale, qb, kb, vtb, vfb);
  hipLaunchKernelGGL(k_attn, dim3(25,NSPLIT,8), dim3(256), 0, stream, qb, kb, vtb, Op, lp);
  hipLaunchKernelGGL(k_mlp,  dim3(TOK_/64),    dim3(256), 0, stream, Op, lp, vfb,
                     projw, fc1w, fc2w, projb, n2w, n2b, fc1b, fc2b, (float*)d_out);
}

// Round 4
// 144.575 us; speedup vs baseline: 1.8313x; 1.8313x over previous
//
#include <hip/hip_runtime.h>
#include <math.h>
#include <stdint.h>

#define B_    8
#define N_    3136
#define DIM_  147
#define KP_   160
#define TOK_  (B_*N_)      // 25088
#define QKV3_ 192
#define NSPLIT 4

typedef __attribute__((ext_vector_type(4)))  float f32x4;
typedef __attribute__((ext_vector_type(16))) float f32x16;
typedef __attribute__((ext_vector_type(4)))  unsigned int u32x4;
typedef __attribute__((ext_vector_type(2)))  unsigned int u32x2;
typedef __attribute__((ext_vector_type(8)))  short short8;
typedef float f32x4u __attribute__((ext_vector_type(4), aligned(4)));  // 4B-aligned vector load
typedef union { short8 s; u32x4 u; } pk8;

static __device__ __forceinline__ unsigned short f2b(float f){
  unsigned int u = __float_as_uint(f);
  u += 0x7fffu + ((u>>16)&1u);          // RNE
  return (unsigned short)(u>>16);
}
static __device__ __forceinline__ unsigned int pk2(float a, float b){   // RNE pack
  return ((unsigned int)f2b(b)<<16) | (unsigned int)f2b(a);
}
static __device__ __forceinline__ unsigned int pk2t(float a, float b){  // trunc pack (P only)
  return (__float_as_uint(b) & 0xffff0000u) | (__float_as_uint(a)>>16);
}
static __device__ __forceinline__ float b2f(unsigned short s){
  return __uint_as_float(((unsigned int)s)<<16);
}

// async global->LDS, 16 B per lane; LDS dest = uniform base + lane*16
#define GLD16(gp, lp) __builtin_amdgcn_global_load_lds( \
    reinterpret_cast<const uint32_t __attribute__((address_space(1)))*>(reinterpret_cast<uintptr_t>(gp)), \
    reinterpret_cast<uint32_t __attribute__((address_space(3)))*>(reinterpret_cast<uintptr_t>(lp)), \
    16, 0, 0)

// ---------------------------------------------------------------- K1: fused LN1 + QKV GEMM
__global__ __launch_bounds__(256) void k_qkv(const float* __restrict__ x,
                                             const float* __restrict__ w1,
                                             const float* __restrict__ b1,
                                             const float* __restrict__ qkvw,
                                             const float* __restrict__ scale,
                                             unsigned short* __restrict__ qb,
                                             unsigned short* __restrict__ kb,
                                             unsigned short* __restrict__ vtb,
                                             unsigned short* __restrict__ vfb){
  __shared__ alignas(16) unsigned short Wb[192*168];  // 64512 B; aliased by A_ and VT
  unsigned short* A_ = Wb;
  unsigned short* VT = Wb;
  int tid = threadIdx.x;
  int w = tid>>6, lane = tid&63, quad = lane>>4, l16 = lane&15;
  int t0 = blockIdx.x*64;
  float sc2 = scale[0] * 1.44269504089f;

  #pragma unroll
  for(int half=0; half<2; half++){
    int g = half*32 + (tid>>3), e = tid&7;
    const float* xr = x + (size_t)(t0+g)*147;
    f32x4u xv[5];
    float s = 0.f, sq = 0.f;
    #pragma unroll
    for(int j=0;j<5;j++){
      int k = e + 8*j;                      // chunk index, cols 4k..4k+3
      int keff = (k > 36) ? 36 : k;         // clamp addr (masked lanes reuse chunk 36)
      f32x4u v = *(const f32x4u*)(xr + 4*keff);
      if(j == 4){                           // k in [32,39]: mask tail
        v[0] = (k<=36) ? v[0] : 0.f;
        v[1] = (k<=36) ? v[1] : 0.f;
        v[2] = (k<=36) ? v[2] : 0.f;
        v[3] = (k< 36) ? v[3] : 0.f;        // col 147 invalid at k==36
      }
      xv[j] = v;
      s  += (v[0]+v[1]) + (v[2]+v[3]);
      sq += (v[0]*v[0]+v[1]*v[1]) + (v[2]*v[2]+v[3]*v[3]);
    }
    s  += __shfl_xor(s,1,64);  s  += __shfl_xor(s,2,64);  s  += __shfl_xor(s,4,64);
    sq += __shfl_xor(sq,1,64); sq += __shfl_xor(sq,2,64); sq += __shfl_xor(sq,4,64);
    float mean = s*(1.f/147.f);
    float var  = sq*(1.f/147.f) - mean*mean;
    float rstd = rsqrtf(var + 1e-5f);
    #pragma unroll
    for(int j=0;j<5;j++){
      int k = e + 8*j;
      unsigned int lo = 0u, hi = 0u;
      if(k <= 36){
        int c0 = 4*k;
        int c3 = (k==36) ? 146 : c0+3;      // don't read w1/b1 past 146
        float y0 = (xv[j][0]-mean)*rstd*w1[c0]   + b1[c0];
        float y1 = (xv[j][1]-mean)*rstd*w1[c0+1] + b1[c0+1];
        float y2 = (xv[j][2]-mean)*rstd*w1[c0+2] + b1[c0+2];
        float y3 = (xv[j][3]-mean)*rstd*w1[c3]   + b1[c3];
        if(k == 36) y3 = 0.f;               // col 147 -> 0 (K padding)
        lo = pk2(y0,y1); hi = pk2(y2,y3);
      }
      *(u32x2*)(A_ + g*168 + 4*k) = (u32x2){lo,hi};   // k>36 lanes zero cols 148..159
    }
  }
  __syncthreads();
  short8 Af[5];
  #pragma unroll
  for(int kk=0;kk<5;kk++)
    Af[kk] = *(const short8*)(A_ + (w*16+l16)*168 + kk*32 + quad*8);
  __syncthreads();
  {
    // stage qkv weights: convert f32 -> bf16 inline
    unsigned int* dst = (unsigned int*)Wb;
    #pragma unroll
    for(int rep=0; rep<15; rep++){
      int idx = rep*256 + tid;
      int row = idx/20, c = idx - row*20;
      u32x4 o = (u32x4){0u,0u,0u,0u};
      if(c < 19){
        const float* sp = qkvw + row*147 + c*8;
        f32x4u a = *(const f32x4u*)sp;
        o[0] = pk2(a[0],a[1]);
        if(c < 18){
          f32x4u bv = *(const f32x4u*)(sp+4);
          o[1] = pk2(a[2],a[3]);
          o[2] = pk2(bv[0],bv[1]);
          o[3] = pk2(bv[2],bv[3]);
        } else {
          o[1] = pk2(a[2],0.f);             // col 147 of row = next row's elem -> masked
        }
      }
      *(u32x4*)(dst + row*84 + c*4) = o;
    }
  }
  __syncthreads();
  f32x4 acc[12];
  #pragma unroll
  for(int i=0;i<12;i++) acc[i] = (f32x4){0.f,0.f,0.f,0.f};
  #pragma unroll
  for(int nt=0;nt<12;nt++){
    #pragma unroll
    for(int kk=0;kk<5;kk++){
      short8 Bf = *(const short8*)(Wb + (nt*16+l16)*168 + kk*32 + quad*8);
      acc[nt] = __builtin_amdgcn_mfma_f32_16x16x32_bf16(Af[kk], Bf, acc[nt], 0,0,0);
    }
  }
  #pragma unroll
  for(int nt=0;nt<12;nt++){
    int o = nt*16 + l16;
    #pragma unroll
    for(int r=0;r<4;r++){
      int tl = w*16 + quad*4 + r;
      int mg = t0 + tl;
      float val = acc[nt][r];
      if(o < 64)        qb[(size_t)mg*64 + o]        = f2b(val*sc2);
      else if(o < 128)  kb[(size_t)mg*64 + (o-64)]   = f2b(val);
      else              vfb[(size_t)mg*64 + (o-128)] = f2b(val);
    }
  }
  __syncthreads();
  #pragma unroll
  for(int nt=8;nt<12;nt++){
    int hd = (nt-8)*16 + l16;
    #pragma unroll
    for(int r=0;r<4;r++)
      VT[hd*72 + (w*16 + quad*4 + r)] = f2b(acc[nt][r]);
  }
  __syncthreads();
  {
    int b = t0 / N_, n0 = t0 - b*N_;
    const unsigned int* VT32 = (const unsigned int*)VT;
    unsigned int* vg = (unsigned int*)vtb + ((size_t)b*64)*(N_/2) + (n0>>1);
    #pragma unroll
    for(int rep=0;rep<8;rep++){
      int f = rep*256 + tid;
      int row = f>>5, c = f&31;
      vg[(size_t)row*(N_/2) + c] = VT32[row*36 + c];
    }
  }
}

// ---------------------------------------------------------------- K2: attention — R13: 4 waves / 128 q-rows per block
// R3 regression root-cause (rocprof): __launch_bounds__(256,4) capped total regs at 128 but the kernel
// needs ~164 (64 acc for O + ~100 arch) -> compiler spilled accumulators to scratch -> FETCH 326MB /
// WRITE 219MB scratch traffic at 3.5TB/s = 158us. Fix: bound (256,2) = 256-reg cap, no spill.
// Occupancy then: VGPR -> 3 blocks/CU, LDS 33KB -> 4; net 12 waves/CU (37.5%), grid 800 = 3.1/CU.
__global__ __launch_bounds__(256,2) void k_attn(const unsigned short* __restrict__ qb,
                                                const unsigned short* __restrict__ kb,
                                                const unsigned short* __restrict__ vtb,
                                                unsigned short* __restrict__ Opart,
                                                float* __restrict__ lpart){
  __shared__ alignas(16) unsigned int L[8192];   // 2 x (K 8KB | V 8KB) dbuf; reused for merge (16KB/pair)
  __shared__ float Lr[256];
  int tid = threadIdx.x;
  int s = tid>>6;                // wave id 0..3
  int w2 = s>>1;                 // q-pair index
  int w  = s&1;                  // kv-half for compute
  int lane = tid&63;
  int h = lane>>5, l32 = lane&31, l7 = l32&7;
  int qt = blockIdx.x, sp = blockIdx.y, b = blockIdx.z;
  int qtile = 2*qt + w2;         // 64-row q tile, 0..48 valid
  int live = (qtile < 49);
  int q0 = live ? qtile*64 : 0;  // clamp dead pair's reads to a valid tile
  int kv0 = (sp*49)>>2, kv1 = ((sp+1)*49)>>2;
  int nt = kv1 - kv0;

  // Q B-frags (32x32x16): n=l32 -> q=q0+32qh+l32; k=8h+i -> hd=16kc+8h+i
  short8 Qf[2][4];
  {
    const unsigned short* qg = qb + ((size_t)b*N_ + q0)*64;
    #pragma unroll
    for(int qh=0;qh<2;qh++)
      #pragma unroll
      for(int kc=0;kc<4;kc++)
        Qf[qh][kc] = *(const short8*)(qg + (32*qh + l32)*64 + 16*kc + 8*h);
  }
  // staging role: waves 0,1 stage K halves; waves 2,3 stage V halves (wh = half index)
  int isK = (s < 2);
  int wh  = s & 1;
  int offG[4];
  {
    int pl = lane>>3, cl = lane&7;
    #pragma unroll
    for(int rr=0;rr<4;rr++){
      int p = rr*8 + pl;
      int cx = cl ^ (p&7);                               // XOR col swizzle
      if(isK){
        int sig = (p & 0x13) | ((p&4)<<1) | ((p&8)>>1);  // swap bits 2<->3
        offG[rr] = (32*wh + sig)*128 + cx*16;            // K: sigma'd row, byte col
      } else {
        offG[rr] = (32*wh + p)*(N_*2) + cx*16;           // V^T: plain hd row
      }
    }
  }
  const char* sBase = isK ? ((const char*)kb  + (size_t)b*N_*128)
                          : ((const char*)vtb + (size_t)b*64*(size_t)(N_*2));
  int tileStride = isK ? 8192 : 128;
  int ldsOff = (isK ? 0 : 8192) + wh*4096;               // within 16KB tile buffer

  f32x16 O[2][2];
  #pragma unroll
  for(int qh=0;qh<2;qh++) for(int hdq=0;hdq<2;hdq++)
    #pragma unroll
    for(int r=0;r<16;r++) O[qh][hdq][r] = 0.f;
  float lracc[2][4];
  #pragma unroll
  for(int qh=0;qh<2;qh++)
    #pragma unroll
    for(int j=0;j<4;j++) lracc[qh][j] = 0.f;

  // prologue: stage tile kv0 into buffer 0 (each wave: its 4KB quarter)
  {
    const char* tp = sBase + (size_t)kv0*tileStride;
    #pragma unroll
    for(int rr=0;rr<4;rr++) GLD16(tp + offG[rr], (char*)L + ldsOff + rr*1024);
  }

  int cur = 0;
  for(int i=0;i<nt;i++){
    int kvt = kv0 + i;
    if(i+1 < nt){
      const char* tp = sBase + (size_t)(kvt+1)*tileStride;
      char* dst = (char*)L + (cur^1)*16384 + ldsOff;
      #pragma unroll
      for(int rr=0;rr<4;rr++) GLD16(tp + offG[rr], dst + rr*1024);
      asm volatile("s_waitcnt vmcnt(4)" ::: "memory");   // current tile's 4 done, next 4 in flight
    } else {
      asm volatile("s_waitcnt vmcnt(0)" ::: "memory");
    }
    __builtin_amdgcn_s_barrier();            // all waves' tile-i LDS quarters visible
    __builtin_amdgcn_sched_barrier(0);       // pin: no ds_read hoisted above barrier

    if(live){
      const unsigned short* Kh = (const unsigned short*)L + cur*8192 + w*2048;
      const unsigned short* Vh = (const unsigned short*)L + cur*8192 + 4096;

      short8 Kf[4];
      #pragma unroll
      for(int kc=0;kc<4;kc++)
        Kf[kc] = *(const short8*)(Kh + l32*64 + (((2*kc+h) ^ l7)&7)*8);
      #pragma unroll
      for(int qh=0;qh<2;qh++){
        f32x16 S;
        #pragma unroll
        for(int r=0;r<16;r++) S[r] = 0.f;
        #pragma unroll
        for(int kc=0;kc<4;kc++)
          S = __builtin_amdgcn_mfma_f32_32x32x16_bf16(Kf[kc], Qf[qh][kc], S, 0,0,0);
        f32x16 E;
        if(kvt == qtile){                // diagonal tile (wave-uniform branch)
          int dref = 32*qh + l32 - 32*w - 8*h;
          #pragma unroll
          for(int r=0;r<16;r++){
            int kvl = 16*((r>>3)&1) + 4*((r>>2)&1) + (r&3);
            float pv = (kvl == dref) ? 0.f : __builtin_amdgcn_exp2f(S[r]);
            E[r] = pv; lracc[qh][r&3] += pv;
          }
        } else {
          #pragma unroll
          for(int r=0;r<16;r++){
            float pv = __builtin_amdgcn_exp2f(S[r]);
            E[r] = pv; lracc[qh][r&3] += pv;
          }
        }
        pk8 Pb0, Pb1;
        Pb0.u = (u32x4){ pk2t(E[0],E[1]),   pk2t(E[2],E[3]),
                         pk2t(E[4],E[5]),   pk2t(E[6],E[7]) };
        Pb1.u = (u32x4){ pk2t(E[8],E[9]),   pk2t(E[10],E[11]),
                         pk2t(E[12],E[13]), pk2t(E[14],E[15]) };
        #pragma unroll
        for(int hdq=0;hdq<2;hdq++){
          short8 Vf0 = *(const short8*)(Vh + (32*hdq + l32)*64 + (((4*w + h) ^ l7)&7)*8);
          short8 Vf1 = *(const short8*)(Vh + (32*hdq + l32)*64 + (((4*w + 2 + h) ^ l7)&7)*8);
          O[qh][hdq] = __builtin_amdgcn_mfma_f32_32x32x16_bf16(Vf0, Pb0.s, O[qh][hdq], 0,0,0);
          O[qh][hdq] = __builtin_amdgcn_mfma_f32_32x32x16_bf16(Vf1, Pb1.s, O[qh][hdq], 0,0,0);
        }
      }
    }
    __builtin_amdgcn_sched_barrier(0);       // pin: no ds_read sunk below WAR barrier
    asm volatile("" ::: "memory");
    __builtin_amdgcn_s_barrier();            // WAR: buf cur free for overwrite at i+1
    cur ^= 1;
  }
  float lr[2];
  #pragma unroll
  for(int qh=0;qh<2;qh++)
    lr[qh] = (lracc[qh][0] + lracc[qh][1]) + (lracc[qh][2] + lracc[qh][3]);
  lr[0] += __shfl_xor(lr[0],32,64);
  lr[1] += __shfl_xor(lr[1],32,64);
  __syncthreads();                     // L free (all tile reads done)
  unsigned int* Lp = L + w2*4096;      // per-pair 16KB merge region
  float* Lrp = Lr + w2*128;
  if(w == 0){
    #pragma unroll
    for(int qh=0;qh<2;qh++)
      #pragma unroll
      for(int hdq=0;hdq<2;hdq++)
        #pragma unroll
        for(int r=0;r<16;r++)
          Lp[(qh*32 + hdq*16 + r)*64 + lane] = __float_as_uint(O[qh][hdq][r]);
    Lrp[lane]      = lr[0];
    Lrp[64 + lane] = lr[1];
  }
  __syncthreads();
  if(w == 1){
    #pragma unroll
    for(int qh=0;qh<2;qh++)
      #pragma unroll
      for(int hdq=0;hdq<2;hdq++)
        #pragma unroll
        for(int r=0;r<16;r++)
          O[qh][hdq][r] += __uint_as_float(Lp[(qh*32 + hdq*16 + r)*64 + lane]);
    float lt0 = lr[0] + Lrp[lane];
    float lt1 = lr[1] + Lrp[64 + lane];
    size_t lb = (size_t)sp*TOK_ + (size_t)b*N_ + q0;
    if(live && lane < 32){ lpart[lb + lane] = lt0; lpart[lb + 32 + lane] = lt1; }
    // transpose O^T -> [q][hd] bf16 in Lp (in-wave DS ordering: reads above precede writes)
    #pragma unroll
    for(int qh=0;qh<2;qh++){
      int q = 32*qh + l32;
      #pragma unroll
      for(int hdq=0;hdq<2;hdq++)
        #pragma unroll
        for(int k2=0;k2<8;k2++){
          int idx = 16*hdq + 4*(k2>>1) + 2*h + (k2&1);
          Lp[q*36 + idx] = pk2(O[qh][hdq][2*k2], O[qh][hdq][2*k2+1]);
        }
    }
    if(live){
      unsigned int* og = (unsigned int*)(Opart + ((size_t)sp*TOK_ + (size_t)b*N_ + q0)*64);
      #pragma unroll
      for(int rep=0;rep<8;rep++){
        int f = rep*64 + lane;
        int row = f>>3, c4 = f&7;
        *(u32x4*)(og + row*32 + c4*4) = *(const u32x4*)&Lp[row*36 + c4*4];
      }
    }
  }
}

// ---------------------------------------------------------------- K3: merge + proj + residual(v) + LN2 + MLP + residual
__global__ __launch_bounds__(256) void k_mlp(const unsigned short* __restrict__ Opart,
                                             const float* __restrict__ lpart,
                                             const unsigned short* __restrict__ vfb,
                                             const float* __restrict__ projw,
                                             const float* __restrict__ fc1w,
                                             const float* __restrict__ fc2w,
                                             const float* __restrict__ projb,
                                             const float* __restrict__ n2w,
                                             const float* __restrict__ n2b,
                                             const float* __restrict__ fc1b,
                                             const float* __restrict__ fc2b,
                                             float* __restrict__ out){
  __shared__ alignas(16) unsigned short Ws[3][64*72];
  __shared__ alignas(16) unsigned short Xs[64*72];
  unsigned int* Xs32 = (unsigned int*)Xs;
  int tid = threadIdx.x;
  int w = tid>>6, lane = tid&63, quad = lane>>4, l16 = lane&15;
  int t0 = blockIdx.x*64;

  {
    #pragma unroll
    for(int rep=0;rep<2;rep++){
      int f = rep*256 + tid;
      int row = f>>3, c = f&7;
      int so = (row<<6) + (c<<3);          // f32 src offset, 16B-aligned
      f32x4 a0 = *(const f32x4*)(projw + so), b0 = *(const f32x4*)(projw + so + 4);
      f32x4 a1 = *(const f32x4*)(fc1w  + so), b1v = *(const f32x4*)(fc1w  + so + 4);
      f32x4 a2 = *(const f32x4*)(fc2w  + so), b2 = *(const f32x4*)(fc2w  + so + 4);
      *(u32x4*)((unsigned int*)Ws[0] + row*36 + c*4) =
        (u32x4){pk2(a0[0],a0[1]),pk2(a0[2],a0[3]),pk2(b0[0],b0[1]),pk2(b0[2],b0[3])};
      *(u32x4*)((unsigned int*)Ws[1] + row*36 + c*4) =
        (u32x4){pk2(a1[0],a1[1]),pk2(a1[2],a1[3]),pk2(b1v[0],b1v[1]),pk2(b1v[2],b1v[3])};
      *(u32x4*)((unsigned int*)Ws[2] + row*36 + c*4) =
        (u32x4){pk2(a2[0],a2[1]),pk2(a2[2],a2[3]),pk2(b2[0],b2[1]),pk2(b2[2],b2[3])};
    }
  }
  #pragma unroll
  for(int i=0;i<2;i++){
    int f = i*256 + tid;
    int row = f>>3, c = f&7;
    float lo[4] = {0,0,0,0}, hi[4] = {0,0,0,0};
    float lsum = 0.f;
    #pragma unroll
    for(int s=0;s<NSPLIT;s++){
      u32x4 a = *((const u32x4*)(Opart + ((size_t)s*TOK_ + t0)*64) + row*8 + c);
      #pragma unroll
      for(int k=0;k<4;k++){
        lo[k] += __uint_as_float(a[k]<<16);
        hi[k] += __uint_as_float(a[k] & 0xffff0000u);
      }
      lsum += lpart[(size_t)s*TOK_ + t0 + row];
    }
    float linv = 1.f/lsum;
    u32x4 o;
    #pragma unroll
    for(int k=0;k<4;k++) o[k] = pk2(lo[k]*linv, hi[k]*linv);
    *(u32x4*)&Xs32[row*36 + c*4] = o;
  }
  __syncthreads();

  short8 Af[2];
  #pragma unroll
  for(int kk=0;kk<2;kk++)
    Af[kk] = *(const short8*)(Xs + (w*16+l16)*72 + kk*32 + quad*8);
  f32x4 acc[4];
  #pragma unroll
  for(int i=0;i<4;i++) acc[i] = (f32x4){0.f,0.f,0.f,0.f};
  #pragma unroll
  for(int jt=0;jt<4;jt++)
    #pragma unroll
    for(int kk=0;kk<2;kk++){
      short8 Bf = *(const short8*)(Ws[0] + (jt*16+l16)*72 + kk*32 + quad*8);
      acc[jt] = __builtin_amdgcn_mfma_f32_16x16x32_bf16(Af[kk], Bf, acc[jt], 0,0,0);
    }
  float xa[4][4];
  #pragma unroll
  for(int jt=0;jt<4;jt++){
    int col = jt*16 + l16;
    float pb = projb[col];
    #pragma unroll
    for(int r=0;r<4;r++){
      int tg = t0 + w*16 + quad*4 + r;
      xa[jt][r] = acc[jt][r] + pb + b2f(vfb[(size_t)tg*64 + col]);
    }
  }
  #pragma unroll
  for(int r=0;r<4;r++){
    float s = 0.f, sq = 0.f;
    #pragma unroll
    for(int jt=0;jt<4;jt++){ s += xa[jt][r]; sq += xa[jt][r]*xa[jt][r]; }
    s  += __shfl_xor(s,1,64);  s  += __shfl_xor(s,2,64);
    s  += __shfl_xor(s,4,64);  s  += __shfl_xor(s,8,64);
    sq += __shfl_xor(sq,1,64); sq += __shfl_xor(sq,2,64);
    sq += __shfl_xor(sq,4,64); sq += __shfl_xor(sq,8,64);
    float mu = s*(1.f/64.f);
    float var = sq*(1.f/64.f) - mu*mu;
    float rstd = rsqrtf(var + 1e-5f);
    #pragma unroll
    for(int jt=0;jt<4;jt++){
      int col = jt*16 + l16;
      Xs[(w*16+quad*4+r)*72 + col] = f2b((xa[jt][r]-mu)*rstd*n2w[col] + n2b[col]);
    }
  }
  #pragma unroll
  for(int kk=0;kk<2;kk++)
    Af[kk] = *(const short8*)(Xs + (w*16+l16)*72 + kk*32 + quad*8);
  f32x4 acc2[4];
  #pragma unroll
  for(int i=0;i<4;i++) acc2[i] = (f32x4){0.f,0.f,0.f,0.f};
  #pragma unroll
  for(int jt=0;jt<4;jt++)
    #pragma unroll
    for(int kk=0;kk<2;kk++){
      short8 Bf = *(const short8*)(Ws[1] + (jt*16+l16)*72 + kk*32 + quad*8);
      acc2[jt] = __builtin_amdgcn_mfma_f32_16x16x32_bf16(Af[kk], Bf, acc2[jt], 0,0,0);
    }
  #pragma unroll
  for(int jt=0;jt<4;jt++){
    int col = jt*16 + l16;
    float fb = fc1b[col];
    #pragma unroll
    for(int r=0;r<4;r++){
      float g = acc2[jt][r] + fb;
      float z = g*0.70710678118f;
      float az = fabsf(z);
      float t = 1.f/(1.f + 0.3275911f*az);
      float poly = ((((1.061405429f*t - 1.453152027f)*t + 1.421413741f)*t - 0.284496736f)*t + 0.254829592f)*t;
      float er = 1.f - poly*__builtin_amdgcn_exp2f(-az*az*1.44269504089f);
      er = (z < 0.f) ? -er : er;
      Xs[(w*16+quad*4+r)*72 + col] = f2b(0.5f*g*(1.f + er));
    }
  }
  #pragma unroll
  for(int kk=0;kk<2;kk++)
    Af[kk] = *(const short8*)(Xs + (w*16+l16)*72 + kk*32 + quad*8);
  f32x4 acc3[4];
  #pragma unroll
  for(int i=0;i<4;i++) acc3[i] = (f32x4){0.f,0.f,0.f,0.f};
  #pragma unroll
  for(int jt=0;jt<4;jt++)
    #pragma unroll
    for(int kk=0;kk<2;kk++){
      short8 Bf = *(const short8*)(Ws[2] + (jt*16+l16)*72 + kk*32 + quad*8);
      acc3[jt] = __builtin_amdgcn_mfma_f32_16x16x32_bf16(Af[kk], Bf, acc3[jt], 0,0,0);
    }
  #pragma unroll
  for(int jt=0;jt<4;jt++){
    int col = jt*16 + l16;
    float ob2 = fc2b[col];
    #pragma unroll
    for(int r=0;r<4;r++){
      int tg = t0 + w*16 + quad*4 + r;
      out[(size_t)tg*64 + col] = xa[jt][r] + acc3[jt][r] + ob2;
    }
  }
}

// ---------------------------------------------------------------- launch
extern "C" void kernel_launch(void* const* d_in, const int* in_sizes, int n_in,
                              void* d_out, int out_size, void* d_ws, size_t ws_size,
                              hipStream_t stream){
  const float* x     = (const float*)d_in[0];
  const float* n1w   = (const float*)d_in[1];
  const float* n1b   = (const float*)d_in[2];
  const float* qkvw  = (const float*)d_in[3];
  const float* scale = (const float*)d_in[4];
  const float* projw = (const float*)d_in[5];
  const float* projb = (const float*)d_in[6];
  const float* n2w   = (const float*)d_in[7];
  const float* n2b   = (const float*)d_in[8];
  const float* fc1w  = (const float*)d_in[9];
  const float* fc1b  = (const float*)d_in[10];
  const float* fc2w  = (const float*)d_in[11];
  const float* fc2b  = (const float*)d_in[12];

  char* base = (char*)d_ws;
  unsigned short* qb  = (unsigned short*)(base + 0);          //  3211264
  unsigned short* kb  = (unsigned short*)(base + 3211264);    //  3211264
  unsigned short* vtb = (unsigned short*)(base + 6422528);    //  3211264
  unsigned short* vfb = (unsigned short*)(base + 9633792);    //  3211264
  unsigned short* Op  = (unsigned short*)(base + 12845056);   // 12845056 (4 splits bf16)
  float*          lp  = (float*)(base + 25690112);            //   401408  -> total 26091520

  hipLaunchKernelGGL(k_qkv,  dim3(TOK_/64),    dim3(256), 0, stream,
                     x, n1w, n1b, qkvw, scale, qb, kb, vtb, vfb);
  hipLaunchKernelGGL(k_attn, dim3(25,NSPLIT,8), dim3(256), 0, stream, qb, kb, vtb, Op, lp);
  hipLaunchKernelGGL(k_mlp,  dim3(TOK_/64),    dim3(256), 0, stream, Op, lp, vfb,
                     projw, fc1w, fc2w, projb, n2w, n2b, fc1b, fc2b, (float*)d_out);
}